// Round 11
// baseline (87.314 us; speedup 1.0000x reference)
//
#include <hip/hip_runtime.h>
#include <hip/hip_bf16.h>
#include <stdint.h>

// CrossAttentionHead: B=8,S=2048,D=1024,HS=64, fp32 in/out, bf16 MFMA internally.
// k0: W -> bf16 fragment-swizzled (scale folded into Wq)
// k1: projections — R10: W resident in LDS (staged once per block), X direct.
//     R1-R9 lesson: per-wave serial VMEM chain (192 loads x ~600cyc) is the
//     floor and the compiler defeats every pipelining attempt. This round
//     shortens the chain 3x: the 128 W-frag loads/wave become ds_read_b128
//     from a 128KB LDS copy staged once per 8-wave block via global_load_lds.
//     X keeps a minimal 2-slot named-reg prefetch (4 live values only).
// k2: flash attention, causal, 4-way k-split per q-tile (flash-decoding merge)

#define NB  8
#define SEQ 2048
#define DIM 1024
#define HSZ 64

typedef short bf16x8 __attribute__((ext_vector_type(8)));
typedef short s16x4  __attribute__((ext_vector_type(4)));
typedef float f32x4  __attribute__((ext_vector_type(4)));

__device__ __forceinline__ short f2bf(float f) {
  __hip_bfloat16 h = __float2bfloat16(f);
  return __builtin_bit_cast(short, h);
}

__device__ __forceinline__ void gld16f(f32x4& d, const float* p) {
  asm volatile("global_load_dwordx4 %0, %1, off" : "=v"(d) : "v"(p));
}

__device__ __forceinline__ void gload_lds16(const void* g, void* l) {
  __builtin_amdgcn_global_load_lds(
      (const __attribute__((address_space(1))) void*)g,
      (__attribute__((address_space(3))) void*)l, 16, 0, 0);
}

// ---------------- Kernel 0: W -> bf16 B-fragment layout -------------------
// idx = (((w*32 + s)*4 + t)*64 + lane)*8 + i
// val = W[k][n]*scale, k = s*32 + (lane>>4)*8 + i, n = t*16 + (lane&15)
__global__ void w_prep(const float* __restrict__ Wq, const float* __restrict__ Wk,
                       const float* __restrict__ Wv, short* __restrict__ wfrag) {
  const int total = 3 << 16;
  for (int e = blockIdx.x * blockDim.x + threadIdx.x; e < total;
       e += gridDim.x * blockDim.x) {
    int i = e & 7, l = (e >> 3) & 63, t = (e >> 9) & 3, s = (e >> 11) & 31, w = e >> 16;
    const float* W = (w == 0) ? Wq : (w == 1) ? Wk : Wv;
    float scale = (w == 0) ? 0.125f : 1.0f;   // fold HS^-0.5 into Wq
    int k = s * 32 + (l >> 4) * 8 + i;
    int n = t * 16 + (l & 15);
    wfrag[e] = f2bf(W[k * HSZ + n] * scale);
  }
}

// ---------------- Kernel 1: projections -----------------------------------
// grid (128, 3), block 512 (8 waves). Block stages the FULL W-fragment table
// (128 KB) into LDS once; each wave then computes one independent 16x64 tile
// over full K=1024 (32 steps), W from ds_read_b128, X via 2-slot prefetch.
__global__ __launch_bounds__(512) void proj(const float* __restrict__ Xq,
                                            const float* __restrict__ Xk,
                                            const float* __restrict__ Xv,
                                            const short* __restrict__ wfrag,
                                            short* __restrict__ qb,
                                            short* __restrict__ kbuf,
                                            short* __restrict__ vT) {
  __shared__ char wlds[131072];   // full W fragment table for this `which`
  const int tid = threadIdx.x;
  const int wave = tid >> 6, lane = tid & 63;
  const int hi = lane >> 4, lo = lane & 15;
  const int which = blockIdx.y;
  const float* X = (which == 0) ? Xq : (which == 1) ? Xk : Xv;
  const char* wf = (const char*)(wfrag + (which << 16));

  // --- stage W once: 512 thr x 16 iters x 16B = 128 KB, contiguous ---
#pragma unroll
  for (int j = 0; j < 16; ++j)
    gload_lds16(wf + (j * 512 + tid) * 16, wlds + (j * 512 + tid) * 16);
  asm volatile("s_waitcnt vmcnt(0)" ::: "memory");
  __syncthreads();

  const int row0 = (blockIdx.x * 8 + wave) * 16;
  const float* xp = X + (size_t)(row0 + lo) * DIM + hi * 8;
  const short* wl = (const short*)wlds + lane * 8;

  f32x4 a0A, a1A, a0B, a1B;
  f32x4 acc0 = {0.f, 0.f, 0.f, 0.f}, acc1 = acc0, acc2 = acc0, acc3 = acc0;

#define COMPUTE(A0, A1, s)                                                     \
  do {                                                                         \
    bf16x8 af_;                                                                \
    af_[0] = f2bf(A0[0]); af_[1] = f2bf(A0[1]);                                \
    af_[2] = f2bf(A0[2]); af_[3] = f2bf(A0[3]);                                \
    af_[4] = f2bf(A1[0]); af_[5] = f2bf(A1[1]);                                \
    af_[6] = f2bf(A1[2]); af_[7] = f2bf(A1[3]);                                \
    const short* wb_ = wl + (s) * 2048;                                        \
    acc0 = __builtin_amdgcn_mfma_f32_16x16x32_bf16(af_, *(const bf16x8*)(wb_),        acc0, 0, 0, 0); \
    acc1 = __builtin_amdgcn_mfma_f32_16x16x32_bf16(af_, *(const bf16x8*)(wb_ + 512),  acc1, 0, 0, 0); \
    acc2 = __builtin_amdgcn_mfma_f32_16x16x32_bf16(af_, *(const bf16x8*)(wb_ + 1024), acc2, 0, 0, 0); \
    acc3 = __builtin_amdgcn_mfma_f32_16x16x32_bf16(af_, *(const bf16x8*)(wb_ + 1536), acc3, 0, 0, 0); \
  } while (0)

  gld16f(a0A, xp);           gld16f(a1A, xp + 4);        // s=0
  gld16f(a0B, xp + 32);      gld16f(a1B, xp + 36);       // s=1

  for (int s = 0; s < 32; s += 2) {
    // invariant at entry: slots A=s, B=s+1; 4 loads outstanding
    asm volatile("s_waitcnt vmcnt(2)" ::: "memory");   // step s lands
    __builtin_amdgcn_sched_barrier(0);
    COMPUTE(a0A, a1A, s);
    if (s + 2 < 32) { gld16f(a0A, xp + (s + 2) * 32); gld16f(a1A, xp + (s + 2) * 32 + 4); }
    if (s + 3 < 32) asm volatile("s_waitcnt vmcnt(2)" ::: "memory");  // s+1 lands
    else            asm volatile("s_waitcnt vmcnt(0)" ::: "memory");
    __builtin_amdgcn_sched_barrier(0);
    COMPUTE(a0B, a1B, s + 1);
    if (s + 3 < 32) { gld16f(a0B, xp + (s + 3) * 32); gld16f(a1B, xp + (s + 3) * 32 + 4); }
  }
#undef COMPUTE

  // --- epilogue: C-layout col = lane&15, row = (lane>>4)*4 + r ---
  if (which < 2) {
    short* ob = (which == 0) ? qb : kbuf;
#pragma unroll
    for (int r = 0; r < 4; ++r) {
      const size_t base = (size_t)(row0 + hi * 4 + r) * HSZ + lo;
      ob[base +  0] = f2bf(acc0[r]);
      ob[base + 16] = f2bf(acc1[r]);
      ob[base + 32] = f2bf(acc2[r]);
      ob[base + 48] = f2bf(acc3[r]);
    }
  } else {
    // vT[b][col][seq]: 4 consecutive seq rows (hi*4+r) are contiguous -> s16x4
    const int b = row0 >> 11;
    const int rloc = (row0 & (SEQ - 1)) + hi * 4;
    short* vbase = vT + (size_t)b * HSZ * SEQ + rloc;
    s16x4 p0, p1, p2, p3;
#pragma unroll
    for (int r = 0; r < 4; ++r) {
      p0[r] = f2bf(acc0[r]); p1[r] = f2bf(acc1[r]);
      p2[r] = f2bf(acc2[r]); p3[r] = f2bf(acc3[r]);
    }
    *(s16x4*)(vbase + (size_t)(lo)      * SEQ) = p0;
    *(s16x4*)(vbase + (size_t)(lo + 16) * SEQ) = p1;
    *(s16x4*)(vbase + (size_t)(lo + 32) * SEQ) = p2;
    *(s16x4*)(vbase + (size_t)(lo + 48) * SEQ) = p3;
  }
}

// ---------------- Kernel 2: causal flash attention -------------------------
// grid 1024 (one block per 16-row q-tile, heavy tiles first), block 256.
// 4 waves split the causal k-block range; flash-decoding merge in LDS.
__global__ __launch_bounds__(256) void attn(const short* __restrict__ qb,
                                            const short* __restrict__ kbuf,
                                            const short* __restrict__ vT,
                                            float* __restrict__ out) {
  __shared__ short plds[4][16 * 32];   // wave-private P staging (bf16)
  __shared__ f32x4 ored[4][16 * 17];   // o partials, f32 stride 68
  __shared__ float mred[4][16];
  __shared__ float lred[4][16];
  const int tid = threadIdx.x;
  const int wave = tid >> 6, lane = tid & 63;
  const int hi = lane >> 4, lo = lane & 15;
  const int bid = blockIdx.x;
  const int tq = 127 - (bid >> 3);    // heavy q-tiles dispatched first
  const int b  = bid & 7;
  const int q0 = tq * 16;

  const short* qp = qb + (size_t)(b * SEQ + q0 + lo) * HSZ + hi * 8;
  const bf16x8 qf0 = *(const bf16x8*)qp;
  const bf16x8 qf1 = *(const bf16x8*)(qp + 32);

  f32x4 o0 = {0.f, 0.f, 0.f, 0.f}, o1 = o0, o2 = o0, o3 = o0;
  f32x4 mrow = {-1e30f, -1e30f, -1e30f, -1e30f};
  f32x4 lrow = {0.f, 0.f, 0.f, 0.f};

  const short* kb_ = kbuf + (size_t)b * SEQ * HSZ;
  const short* vb_ = vT + (size_t)b * HSZ * SEQ;
  short* pl = plds[wave];
  const int nkb = (q0 + 47) >> 5;
  const int chunk = (nkb + 3) >> 2;
  const int kks = wave * chunk;
  const int kke = min(kks + chunk, nkb);

  for (int kk = kks; kk < kke; ++kk) {
    const int kc0 = kk * 32;
    const short* kr0 = kb_ + (size_t)(kc0 + lo) * HSZ + hi * 8;
    const short* kr1 = kr0 + 16 * HSZ;
    f32x4 s0v = {0.f, 0.f, 0.f, 0.f}, s1v = s0v;
    s0v = __builtin_amdgcn_mfma_f32_16x16x32_bf16(qf0, *(const bf16x8*)kr0, s0v, 0, 0, 0);
    s0v = __builtin_amdgcn_mfma_f32_16x16x32_bf16(qf1, *(const bf16x8*)(kr0 + 32), s0v, 0, 0, 0);
    s1v = __builtin_amdgcn_mfma_f32_16x16x32_bf16(qf0, *(const bf16x8*)kr1, s1v, 0, 0, 0);
    s1v = __builtin_amdgcn_mfma_f32_16x16x32_bf16(qf1, *(const bf16x8*)(kr1 + 32), s1v, 0, 0, 0);

    const bool edge = (kc0 + 31 > q0);
#pragma unroll
    for (int r = 0; r < 4; ++r) {
      const int row = q0 + hi * 4 + r;
      float s0 = s0v[r], s1 = s1v[r];
      if (edge) {
        if (kc0 + lo > row)      s0 = -1e30f;
        if (kc0 + 16 + lo > row) s1 = -1e30f;
      }
      float pm = fmaxf(s0, s1);
      pm = fmaxf(pm, __shfl_xor(pm, 1, 16));
      pm = fmaxf(pm, __shfl_xor(pm, 2, 16));
      pm = fmaxf(pm, __shfl_xor(pm, 4, 16));
      pm = fmaxf(pm, __shfl_xor(pm, 8, 16));
      const float mn  = fmaxf(mrow[r], pm);
      const float fac = __expf(mrow[r] - mn);
      mrow[r] = mn;
      const float p0 = __expf(s0 - mn), p1 = __expf(s1 - mn);
      float ps = p0 + p1;
      ps += __shfl_xor(ps, 1, 16);
      ps += __shfl_xor(ps, 2, 16);
      ps += __shfl_xor(ps, 4, 16);
      ps += __shfl_xor(ps, 8, 16);
      lrow[r] = lrow[r] * fac + ps;
      o0[r] *= fac; o1[r] *= fac; o2[r] *= fac; o3[r] *= fac;
      pl[(hi * 4 + r) * 32 + lo]      = f2bf(p0);
      pl[(hi * 4 + r) * 32 + 16 + lo] = f2bf(p1);
    }
    const bf16x8 pa = *(const bf16x8*)(pl + lo * 32 + hi * 8);
    const short* vr = vb_ + (size_t)lo * SEQ + kc0 + hi * 8;
    o0 = __builtin_amdgcn_mfma_f32_16x16x32_bf16(pa, *(const bf16x8*)(vr), o0, 0, 0, 0);
    o1 = __builtin_amdgcn_mfma_f32_16x16x32_bf16(pa, *(const bf16x8*)(vr + 16 * SEQ), o1, 0, 0, 0);
    o2 = __builtin_amdgcn_mfma_f32_16x16x32_bf16(pa, *(const bf16x8*)(vr + 32 * SEQ), o2, 0, 0, 0);
    o3 = __builtin_amdgcn_mfma_f32_16x16x32_bf16(pa, *(const bf16x8*)(vr + 48 * SEQ), o3, 0, 0, 0);
  }

  // partials -> LDS
  float* redf = (float*)&ored[wave][0];
#pragma unroll
  for (int r = 0; r < 4; ++r) {
    const int row = hi * 4 + r;
    redf[row * 68 + lo]      = o0[r];
    redf[row * 68 + 16 + lo] = o1[r];
    redf[row * 68 + 32 + lo] = o2[r];
    redf[row * 68 + 48 + lo] = o3[r];
  }
  if (lo == 0) {
#pragma unroll
    for (int r = 0; r < 4; ++r) {
      mred[wave][hi * 4 + r] = mrow[r];
      lred[wave][hi * 4 + r] = lrow[r];
    }
  }
  __syncthreads();

  // flash-decoding merge across the 4 k-splits
  const int row = tid >> 4, cg = tid & 15;
  float mv0 = mred[0][row], mv1 = mred[1][row], mv2 = mred[2][row], mv3 = mred[3][row];
  float M = fmaxf(fmaxf(mv0, mv1), fmaxf(mv2, mv3));
  const float w0 = __expf(mv0 - M), w1 = __expf(mv1 - M);
  const float w2 = __expf(mv2 - M), w3 = __expf(mv3 - M);
  const float L = lred[0][row] * w0 + lred[1][row] * w1 +
                  lred[2][row] * w2 + lred[3][row] * w3;
  f32x4 acc = ored[0][row * 17 + cg] * w0 + ored[1][row * 17 + cg] * w1 +
              ored[2][row * 17 + cg] * w2 + ored[3][row * 17 + cg] * w3;
  acc *= (1.0f / L);
  *(f32x4*)(out + ((size_t)(b * SEQ + q0 + row)) * HSZ + cg * 4) = acc;
}

extern "C" void kernel_launch(void* const* d_in, const int* in_sizes, int n_in,
                              void* d_out, int out_size, void* d_ws, size_t ws_size,
                              hipStream_t stream) {
  const float* query = (const float*)d_in[0];
  const float* key   = (const float*)d_in[1];
  const float* value = (const float*)d_in[2];
  const float* Wq    = (const float*)d_in[3];
  const float* Wk    = (const float*)d_in[4];
  const float* Wv    = (const float*)d_in[5];

  char* ws = (char*)d_ws;
  short* wfrag = (short*)ws;                                  // 384 KiB
  short* qb    = (short*)(ws + (3 << 17));                    // 2 MiB
  short* kb    = (short*)(ws + (3 << 17) + (1 << 21));        // 2 MiB
  short* vT    = (short*)(ws + (3 << 17) + (2 << 21));        // 2 MiB
  float* outp  = (float*)d_out;

  hipLaunchKernelGGL(w_prep, dim3(64), dim3(256), 0, stream, Wq, Wk, Wv, wfrag);
  hipLaunchKernelGGL(proj, dim3(128, 3), dim3(512), 0, stream,
                     query, key, value, wfrag, qb, kb, vT);
  hipLaunchKernelGGL(attn, dim3(1024), dim3(256), 0, stream, qb, kb, vT, outp);
}